// Round 6
// baseline (90.726 us; speedup 1.0000x reference)
//
#include <hip/hip_runtime.h>
#include <hip/hip_bf16.h>

#define BB 16
#define LCTX 2048
#define DDIM 1024
#define QDIM 1024
#define HDIM 256

typedef __attribute__((ext_vector_type(8))) short short8;
typedef __attribute__((ext_vector_type(4))) float f32x4;

__device__ inline unsigned short f2bf(float x) {
    unsigned int u = __float_as_uint(x);
    unsigned int r = (u + 0x7fffu + ((u >> 16) & 1u)) >> 16;
    return (unsigned short)r;
}

// ---------------- K1: fused prep ----------------
// bid <  1024 : qproj[b][h] = query[b] . Wq[h] + b1[h]
// 1024..1279  : Wc row (h) -> bf16, k-major layout [kt][h][oct][8]
// bid == 1280 : w2 = g * v / ||v||
__global__ __launch_bounds__(256) void k_prep(const float* __restrict__ query,
                                              const float* __restrict__ W1,
                                              const float* __restrict__ b1,
                                              const float* __restrict__ v,
                                              const float* __restrict__ g,
                                              float* __restrict__ qproj,
                                              unsigned short* __restrict__ Wc_kmaj,
                                              float* __restrict__ w2) {
    int bid = blockIdx.x;
    if (bid < 1024) {
        int b = bid >> 6;
        int hq = bid & 63;
        int wid = threadIdx.x >> 6, lane = threadIdx.x & 63;
        int h = hq * 4 + wid;
        const float* q = query + b * QDIM;
        const float* w = W1 + (size_t)h * (DDIM + QDIM) + DDIM;
        float s = 0.f;
        #pragma unroll 4
        for (int k = lane; k < QDIM; k += 64) s += q[k] * w[k];
        #pragma unroll
        for (int o = 32; o; o >>= 1) s += __shfl_down(s, o);
        if (lane == 0) qproj[b * HDIM + h] = s + b1[h];
    } else if (bid < 1280) {
        int h = bid - 1024;
        const float* src = W1 + (size_t)h * (DDIM + QDIM);
        for (int d = threadIdx.x; d < DDIM; d += 256) {
            int kt = d >> 6;
            int oct = (d >> 3) & 7;
            int j = d & 7;
            Wc_kmaj[(size_t)kt * 16384 + h * 64 + oct * 8 + j] = f2bf(src[d]);
        }
    } else {
        __shared__ float red[256];
        float vv = (threadIdx.x < HDIM) ? v[threadIdx.x] : 0.f;
        red[threadIdx.x] = vv * vv;
        __syncthreads();
        for (int o = 128; o; o >>= 1) {
            if (threadIdx.x < o) red[threadIdx.x] += red[threadIdx.x + o];
            __syncthreads();
        }
        float nrm = sqrtf(red[0]);
        if (threadIdx.x < HDIM) w2[threadIdx.x] = g[0] * vv / nrm;
    }
}

// ---------------- K2: score GEMM, granule-staged ctx ----------------
// Block = 64 rows. ctx staged in 4 granules of 256 cols: each thread reads
// 1 KB CONTIGUOUS per row-granule (DRAM row-activation amortized 4x vs 256 B).
// At dbuf 2x32 KB (XOR-swizzled). W fragments load straight from L2 (k-major
// global layout, coalesced) -- no W LDS, no global_load_lds, 1 barrier/granule.
__global__ __launch_bounds__(256, 2) void k_score(const float* __restrict__ ctx,
                                                  const unsigned short* __restrict__ Wc_kmaj,
                                                  const float* __restrict__ qproj,
                                                  const float* __restrict__ w2,
                                                  const float* __restrict__ b2p,
                                                  const int* __restrict__ mask,
                                                  float* __restrict__ e_ws,
                                                  float* __restrict__ esum_ws) {
    __shared__ unsigned short At[2][64 * 256];   // 2 x 32 KB, 256 bf16/row (one granule)
    int tid = threadIdx.x;
    int wid = tid >> 6, lane = tid & 63;
    int hl = lane & 15, lhi = lane >> 4;
    int row0 = blockIdx.x * 64;
    int b = row0 >> 11;

    f32x4 acc[4][4];
    #pragma unroll
    for (int mt = 0; mt < 4; mt++)
        #pragma unroll
        for (int ht = 0; ht < 4; ht++)
            acc[mt][ht] = (f32x4){0.f, 0.f, 0.f, 0.f};

    int srow = tid >> 2;        // staged row 0..63
    int q = tid & 3;            // 64-float column quarter within granule
    int sxr = srow & 7;
    const float* csrc = ctx + (size_t)(row0 + srow) * DDIM + q * 64;

    // stage granule G (256 cols) into buffer BUF: 16 sequential float4 per thread
#define STAGE(BUF, G) do { \
    const float* sp_ = csrc + (G) * 256; \
    _Pragma("unroll") \
    for (int bat_ = 0; bat_ < 4; bat_++) { \
        float4 v0_ = *(const float4*)(sp_ + bat_ * 16 + 0); \
        float4 v1_ = *(const float4*)(sp_ + bat_ * 16 + 4); \
        float4 v2_ = *(const float4*)(sp_ + bat_ * 16 + 8); \
        float4 v3_ = *(const float4*)(sp_ + bat_ * 16 + 12); \
        short8 h0_ = { (short)f2bf(v0_.x), (short)f2bf(v0_.y), (short)f2bf(v0_.z), (short)f2bf(v0_.w), \
                       (short)f2bf(v1_.x), (short)f2bf(v1_.y), (short)f2bf(v1_.z), (short)f2bf(v1_.w) }; \
        short8 h1_ = { (short)f2bf(v2_.x), (short)f2bf(v2_.y), (short)f2bf(v2_.z), (short)f2bf(v2_.w), \
                       (short)f2bf(v3_.x), (short)f2bf(v3_.y), (short)f2bf(v3_.z), (short)f2bf(v3_.w) }; \
        int o0_ = (q * 8 + bat_ * 2 + 0) ^ sxr; \
        int o1_ = (q * 8 + bat_ * 2 + 1) ^ sxr; \
        *(short8*)(&At[BUF][srow * 256 + o0_ * 8]) = h0_; \
        *(short8*)(&At[BUF][srow * 256 + o1_ * 8]) = h1_; \
    } } while (0)

    // compute granule G from buffer BUF: 4 k-tiles x 2 k-halves x 16 MFMA
#define COMPUTE(BUF, G) do { \
    _Pragma("unroll") \
    for (int kt_ = 0; kt_ < 4; kt_++) { \
        int ktg_ = (G) * 4 + kt_; \
        _Pragma("unroll") \
        for (int ks_ = 0; ks_ < 2; ks_++) { \
            int sl_ = kt_ * 8 + ks_ * 4 + lhi; \
            short8 af_[4], bf_[4]; \
            _Pragma("unroll") \
            for (int mt_ = 0; mt_ < 4; mt_++) { \
                int m_ = mt_ * 16 + hl; \
                af_[mt_] = *(const short8*)(&At[BUF][m_ * 256 + (sl_ ^ (m_ & 7)) * 8]); \
            } \
            _Pragma("unroll") \
            for (int ht_ = 0; ht_ < 4; ht_++) { \
                int h_ = wid * 64 + ht_ * 16 + hl; \
                bf_[ht_] = *(const short8*)(Wc_kmaj + (size_t)ktg_ * 16384 + h_ * 64 + (ks_ * 4 + lhi) * 8); \
            } \
            _Pragma("unroll") \
            for (int mt_ = 0; mt_ < 4; mt_++) \
                _Pragma("unroll") \
                for (int ht_ = 0; ht_ < 4; ht_++) \
                    acc[mt_][ht_] = __builtin_amdgcn_mfma_f32_16x16x32_bf16(af_[mt_], bf_[ht_], acc[mt_][ht_], 0, 0, 0); \
        } } } while (0)

    STAGE(0, 0);
    __syncthreads();
    COMPUTE(0, 0); STAGE(1, 1); __syncthreads();
    COMPUTE(1, 1); STAGE(0, 2); __syncthreads();
    COMPUTE(0, 2); STAGE(1, 3); __syncthreads();
    COMPUTE(1, 3);
    __syncthreads();

    // ---- epilogue: tanh + w2 dot, 16-lane reduce, cross-wave via LDS ----
    float qp[4], wv[4];
    #pragma unroll
    for (int ht = 0; ht < 4; ht++) {
        int h = wid * 64 + ht * 16 + hl;
        qp[ht] = qproj[b * HDIM + h];
        wv[ht] = w2[h];
    }
    float* sb  = (float*)At;      // 256 floats cross-wave partials
    float* sbe = sb + 256;        // 64 floats e per row
    #pragma unroll
    for (int mt = 0; mt < 4; mt++) {
        #pragma unroll
        for (int r = 0; r < 4; r++) {
            float partial = 0.f;
            #pragma unroll
            for (int ht = 0; ht < 4; ht++) {
                float x = acc[mt][ht][r] + qp[ht];
                x = fminf(fmaxf(x, -15.f), 15.f);
                float e2 = __expf(2.f * x);
                partial += (e2 - 1.f) / (e2 + 1.f) * wv[ht];
            }
            #pragma unroll
            for (int o = 1; o < 16; o <<= 1) partial += __shfl_xor(partial, o);
            if (hl == 0) sb[wid * 64 + mt * 16 + lhi * 4 + r] = partial;
        }
    }
    __syncthreads();

    if (tid < 64) {
        float s = sb[tid] + sb[64 + tid] + sb[128 + tid] + sb[192 + tid] + b2p[0];
        int grow = row0 + tid;
        float e = (mask[b * 2048 + (grow & 2047)] == 1) ? 0.f : __expf(s);
        e_ws[grow] = e;
        sbe[tid] = e;
        float tot = e;
        #pragma unroll
        for (int o = 32; o; o >>= 1) tot += __shfl_down(tot, o);
        if (tid == 0) esum_ws[blockIdx.x] = tot;
    }
}

// ---------------- K3: expected-ctx partials (full-row sequential reads) ----------------
// grid (16, 32): block (b, ls) covers 64 rows. Wave reads whole 4 KB rows
// sequentially; lane owns d in [lane*16, lane*16+16).
__global__ __launch_bounds__(256) void k_exp(const float* __restrict__ ctx,
                                             const float* __restrict__ e_ws,
                                             float* __restrict__ part) {
    int b = blockIdx.x, ls = blockIdx.y;
    int wid = threadIdx.x >> 6, lane = threadIdx.x & 63;
    __shared__ float red[4][1024];

    f32x4 a0 = {0,0,0,0}, a1 = {0,0,0,0}, a2 = {0,0,0,0}, a3 = {0,0,0,0};
    const float* base = ctx + ((size_t)b * LCTX + ls * 64 + wid * 16) * DDIM + lane * 16;
    const float* ep = e_ws + b * LCTX + ls * 64 + wid * 16;

    #pragma unroll 4
    for (int i = 0; i < 16; i++) {
        float e = ep[i];
        const f32x4* p = (const f32x4*)(base + (size_t)i * DDIM);
        f32x4 v0 = p[0], v1 = p[1], v2 = p[2], v3 = p[3];
        a0 += e * v0; a1 += e * v1; a2 += e * v2; a3 += e * v3;
    }
    *(f32x4*)(&red[wid][lane * 16 + 0])  = a0;
    *(f32x4*)(&red[wid][lane * 16 + 4])  = a1;
    *(f32x4*)(&red[wid][lane * 16 + 8])  = a2;
    *(f32x4*)(&red[wid][lane * 16 + 12]) = a3;
    __syncthreads();

    int d0 = threadIdx.x * 4;
    f32x4 s = *(const f32x4*)(&red[0][d0]);
    s += *(const f32x4*)(&red[1][d0]);
    s += *(const f32x4*)(&red[2][d0]);
    s += *(const f32x4*)(&red[3][d0]);
    *(f32x4*)(part + ((size_t)(b * 32 + ls)) * DDIM + d0) = s;
}

// ---------------- K4: normalize -> out_exp, out_p ----------------
__global__ __launch_bounds__(256) void k_norm(const float* __restrict__ e_ws,
                                              const float* __restrict__ esum_ws,
                                              const float* __restrict__ part,
                                              float* __restrict__ out_exp,
                                              float* __restrict__ out_p) {
    int b = blockIdx.x, dc = blockIdx.y;
    int tid = threadIdx.x;
    float se = 0.f;
    #pragma unroll
    for (int j = 0; j < 32; j++) se += esum_ws[b * 32 + j];
    float inv = 1.f / se;
    if (tid < 128) {
        int d = dc * 128 + tid;
        float s = 0.f;
        #pragma unroll
        for (int j = 0; j < 32; j++) s += part[(size_t)(b * 32 + j) * DDIM + d];
        out_exp[b * DDIM + d] = s * inv;
    }
    int l = dc * 256 + tid;
    out_p[b * LCTX + l] = e_ws[b * LCTX + l] * inv;
}

extern "C" void kernel_launch(void* const* d_in, const int* in_sizes, int n_in,
                              void* d_out, int out_size, void* d_ws, size_t ws_size,
                              hipStream_t stream) {
    const float* ctx   = (const float*)d_in[0];
    const float* query = (const float*)d_in[1];
    const int*   mask  = (const int*)d_in[2];
    const float* W1    = (const float*)d_in[3];
    const float* b1    = (const float*)d_in[4];
    const float* v     = (const float*)d_in[5];
    const float* g     = (const float*)d_in[6];
    const float* b2    = (const float*)d_in[7];
    float* out_exp = (float*)d_out;              // [16,1024]
    float* out_p   = (float*)d_out + 16384;      // [16,2048]

    char* ws = (char*)d_ws;
    unsigned short* Wc_kmaj = (unsigned short*)ws;        // 512 KB
    float* qproj = (float*)(ws + 524288);                 // 16 KB
    float* w2    = (float*)(ws + 540672);                 // 1 KB
    float* e_ws  = (float*)(ws + 541696);                 // 128 KB (16x2048)
    float* esum  = (float*)(ws + 672768);                 // 2 KB  (512)
    float* part  = (float*)(ws + 674816);                 // 2 MB  (512x1024)

    k_prep <<<dim3(1281),    256, 0, stream>>>(query, W1, b1, v, g, qproj, Wc_kmaj, w2);
    k_score<<<dim3(512),     256, 0, stream>>>(ctx, Wc_kmaj, qproj, w2, b2, mask, e_ws, esum);
    k_exp  <<<dim3(16, 32),  256, 0, stream>>>(ctx, e_ws, part);
    k_norm <<<dim3(16, 8),   256, 0, stream>>>(e_ws, esum, part, out_exp, out_p);
}

// Round 7
// 70.065 us; speedup vs baseline: 1.2949x; 1.2949x over previous
//
#include <hip/hip_runtime.h>
#include <hip/hip_bf16.h>

#define BB 16
#define LCTX 2048
#define DDIM 1024
#define QDIM 1024
#define HDIM 256

typedef __attribute__((ext_vector_type(8))) short short8;
typedef __attribute__((ext_vector_type(4))) float f32x4;

__device__ inline unsigned short f2bf(float x) {
    unsigned int u = __float_as_uint(x);
    unsigned int r = (u + 0x7fffu + ((u >> 16) & 1u)) >> 16;
    return (unsigned short)r;
}

// ---------------- K1: fused prep ----------------
// bid <  1024 : qproj[b][h] = query[b] . Wq[h] + b1[h]
// 1024..1279  : Wc row (h) -> bf16, chunks pre-swizzled for LDS (row-major)
// bid == 1280 : w2 = g * v / ||v||
__global__ __launch_bounds__(256) void k_prep(const float* __restrict__ query,
                                              const float* __restrict__ W1,
                                              const float* __restrict__ b1,
                                              const float* __restrict__ v,
                                              const float* __restrict__ g,
                                              float* __restrict__ qproj,
                                              unsigned short* __restrict__ Wc_sw,
                                              float* __restrict__ w2) {
    int bid = blockIdx.x;
    if (bid < 1024) {
        int b = bid >> 6;
        int hq = bid & 63;
        int wid = threadIdx.x >> 6, lane = threadIdx.x & 63;
        int h = hq * 4 + wid;
        const float* q = query + b * QDIM;
        const float* w = W1 + (size_t)h * (DDIM + QDIM) + DDIM;
        float s = 0.f;
        #pragma unroll 4
        for (int k = lane; k < QDIM; k += 64) s += q[k] * w[k];
        #pragma unroll
        for (int o = 32; o; o >>= 1) s += __shfl_down(s, o);
        if (lane == 0) qproj[b * HDIM + h] = s + b1[h];
    } else if (bid < 1280) {
        int h = bid - 1024;
        const float* src = W1 + (size_t)h * (DDIM + QDIM);
        int hx = h & 7;
        for (int d = threadIdx.x; d < DDIM; d += 256) {
            int kt = d >> 6;
            int s  = (d >> 3) & 7;      // 16B chunk within 64-col k-tile
            int dl = d & 7;
            int dp = (kt << 6) + ((s ^ hx) << 3) + dl;
            Wc_sw[h * DDIM + dp] = f2bf(src[d]);
        }
    } else {
        __shared__ float red[256];
        float vv = (threadIdx.x < HDIM) ? v[threadIdx.x] : 0.f;
        red[threadIdx.x] = vv * vv;
        __syncthreads();
        for (int o = 128; o; o >>= 1) {
            if (threadIdx.x < o) red[threadIdx.x] += red[threadIdx.x + o];
            __syncthreads();
        }
        float nrm = sqrtf(red[0]);
        if (threadIdx.x < HDIM) w2[threadIdx.x] = g[0] * vv / nrm;
    }
}

// ---------------- K2: score GEMM + tanh/exp epilogue ONLY (no fused GEMV) ----------------
// Round-2 structure: 64-row tile, W via global_load_lds (pre-swizzled source),
// ctx reg->bf16->swizzled LDS, 2 barriers/K-step. Ablation: the GEMV epilogue
// that dominated rounds 2-6 is moved back out to k_exp.
__global__ __launch_bounds__(256, 3) void k_score(const float* __restrict__ ctx,
                                                  const unsigned short* __restrict__ Wc_sw,
                                                  const float* __restrict__ qproj,
                                                  const float* __restrict__ w2,
                                                  const float* __restrict__ b2p,
                                                  const int* __restrict__ mask,
                                                  float* __restrict__ e_ws,
                                                  float* __restrict__ esum_ws) {
    __shared__ unsigned short At[64 * 64];    // 8 KB, XOR-swizzled
    __shared__ unsigned short Wt[256 * 64];   // 32 KB, pre-swizzled in global
    int tid = threadIdx.x;
    int wid = tid >> 6, lane = tid & 63;
    int hl = lane & 15, lhi = lane >> 4;
    int bid = blockIdx.x;
    int row0 = bid * 64;
    int b = row0 >> 11;

    float qp[4], wv[4];
    #pragma unroll
    for (int ht = 0; ht < 4; ht++) {
        int h = wid * 64 + ht * 16 + hl;
        qp[ht] = qproj[b * HDIM + h];
        wv[ht] = w2[h];
    }

    f32x4 acc[4][4];
    #pragma unroll
    for (int mt = 0; mt < 4; mt++)
        #pragma unroll
        for (int ht = 0; ht < 4; ht++)
            acc[mt][ht] = (f32x4){0.f, 0.f, 0.f, 0.f};

    int srow = tid >> 2;            // 0..63 tile row this thread stages
    int c0 = (tid & 3) * 2;         // first 16B chunk index
    int sx = srow & 7;
    const float* csrc = ctx + (size_t)(row0 + srow) * DDIM + (tid & 3) * 16;

    for (int kt = 0; kt < 16; kt++) {
        // stage W tile: 32 KB via global_load_lds (linear dest; src pre-swizzled)
        #pragma unroll
        for (int i = 0; i < 8; i++) {
            int n = i * 256 + tid;
            const unsigned short* gsrc = Wc_sw + (size_t)(n >> 3) * DDIM + kt * 64 + (n & 7) * 8;
            __builtin_amdgcn_global_load_lds(
                (const __attribute__((address_space(1))) unsigned int*)gsrc,
                (__attribute__((address_space(3))) unsigned int*)(Wt + (i * 256 + (tid & ~63)) * 8),
                16, 0, 0);
        }
        // stage ctx tile: f32 -> bf16 -> swizzled LDS
        const float* cp = csrc + kt * 64;
        float4 cv0 = *(const float4*)(cp + 0);
        float4 cv1 = *(const float4*)(cp + 4);
        float4 cv2 = *(const float4*)(cp + 8);
        float4 cv3 = *(const float4*)(cp + 12);
        short8 p0 = { (short)f2bf(cv0.x), (short)f2bf(cv0.y), (short)f2bf(cv0.z), (short)f2bf(cv0.w),
                      (short)f2bf(cv1.x), (short)f2bf(cv1.y), (short)f2bf(cv1.z), (short)f2bf(cv1.w) };
        short8 p1 = { (short)f2bf(cv2.x), (short)f2bf(cv2.y), (short)f2bf(cv2.z), (short)f2bf(cv2.w),
                      (short)f2bf(cv3.x), (short)f2bf(cv3.y), (short)f2bf(cv3.z), (short)f2bf(cv3.w) };
        *(short8*)(At + srow * 64 + (((c0 + 0) ^ sx) << 3)) = p0;
        *(short8*)(At + srow * 64 + (((c0 + 1) ^ sx) << 3)) = p1;
        __syncthreads();

        #pragma unroll
        for (int ks = 0; ks < 2; ks++) {
            int s = ks * 4 + lhi;
            short8 af[4], bfr[4];
            #pragma unroll
            for (int mt = 0; mt < 4; mt++) {
                int m = mt * 16 + hl;
                af[mt] = *(const short8*)(At + m * 64 + ((s ^ (m & 7)) << 3));
            }
            #pragma unroll
            for (int ht = 0; ht < 4; ht++) {
                int h = wid * 64 + ht * 16 + hl;
                bfr[ht] = *(const short8*)(Wt + h * 64 + ((s ^ (h & 7)) << 3));
            }
            #pragma unroll
            for (int mt = 0; mt < 4; mt++)
                #pragma unroll
                for (int ht = 0; ht < 4; ht++)
                    acc[mt][ht] = __builtin_amdgcn_mfma_f32_16x16x32_bf16(af[mt], bfr[ht], acc[mt][ht], 0, 0, 0);
        }
        __syncthreads();
    }

    // ---- epilogue 1: tanh + w2 dot, reduce 16 lanes, cross-wave via LDS ----
    float* sb  = (float*)At;
    #pragma unroll
    for (int mt = 0; mt < 4; mt++) {
        #pragma unroll
        for (int r = 0; r < 4; r++) {
            float partial = 0.f;
            #pragma unroll
            for (int ht = 0; ht < 4; ht++) {
                float x = acc[mt][ht][r] + qp[ht];
                x = fminf(fmaxf(x, -15.f), 15.f);
                float e2 = __expf(2.f * x);
                partial += (e2 - 1.f) / (e2 + 1.f) * wv[ht];
            }
            #pragma unroll
            for (int o = 1; o < 16; o <<= 1) partial += __shfl_xor(partial, o);
            if (hl == 0) sb[wid * 64 + mt * 16 + lhi * 4 + r] = partial;
        }
    }
    __syncthreads();

    // ---- epilogue 2: score -> e = exp(score) (masked -> 0) ----
    if (tid < 64) {
        float s = sb[tid] + sb[64 + tid] + sb[128 + tid] + sb[192 + tid] + b2p[0];
        int grow = row0 + tid;
        float e = (mask[b * 2048 + (grow & 2047)] == 1) ? 0.f : __expf(s);
        e_ws[grow] = e;
        float tot = e;
        #pragma unroll
        for (int o = 32; o; o >>= 1) tot += __shfl_down(tot, o);
        if (tid == 0) esum_ws[bid] = tot;
    }
}

// ---------------- K3: expected-ctx partials (full-row sequential reads) ----------------
// grid (16, 32): block (b, ls) covers 64 rows; wave reads whole 4 KB rows.
__global__ __launch_bounds__(256) void k_exp(const float* __restrict__ ctx,
                                             const float* __restrict__ e_ws,
                                             float* __restrict__ part) {
    int b = blockIdx.x, ls = blockIdx.y;
    int wid = threadIdx.x >> 6, lane = threadIdx.x & 63;
    __shared__ float red[4][1024];

    f32x4 a0 = {0,0,0,0}, a1 = {0,0,0,0}, a2 = {0,0,0,0}, a3 = {0,0,0,0};
    const float* base = ctx + ((size_t)b * LCTX + ls * 64 + wid * 16) * DDIM + lane * 16;
    const float* ep = e_ws + b * LCTX + ls * 64 + wid * 16;

    #pragma unroll 4
    for (int i = 0; i < 16; i++) {
        float e = ep[i];
        const f32x4* p = (const f32x4*)(base + (size_t)i * DDIM);
        f32x4 v0 = p[0], v1 = p[1], v2 = p[2], v3 = p[3];
        a0 += e * v0; a1 += e * v1; a2 += e * v2; a3 += e * v3;
    }
    *(f32x4*)(&red[wid][lane * 16 + 0])  = a0;
    *(f32x4*)(&red[wid][lane * 16 + 4])  = a1;
    *(f32x4*)(&red[wid][lane * 16 + 8])  = a2;
    *(f32x4*)(&red[wid][lane * 16 + 12]) = a3;
    __syncthreads();

    int d0 = threadIdx.x * 4;
    f32x4 s = *(const f32x4*)(&red[0][d0]);
    s += *(const f32x4*)(&red[1][d0]);
    s += *(const f32x4*)(&red[2][d0]);
    s += *(const f32x4*)(&red[3][d0]);
    *(f32x4*)(part + ((size_t)(b * 32 + ls)) * DDIM + d0) = s;
}

// ---------------- K4: normalize -> out_exp, out_p ----------------
__global__ __launch_bounds__(256) void k_norm(const float* __restrict__ e_ws,
                                              const float* __restrict__ esum_ws,
                                              const float* __restrict__ part,
                                              float* __restrict__ out_exp,
                                              float* __restrict__ out_p) {
    int b = blockIdx.x, dc = blockIdx.y;
    int tid = threadIdx.x;
    float se = 0.f;
    #pragma unroll
    for (int j = 0; j < 32; j++) se += esum_ws[b * 32 + j];
    float inv = 1.f / se;
    if (tid < 128) {
        int d = dc * 128 + tid;
        float s = 0.f;
        #pragma unroll
        for (int j = 0; j < 32; j++) s += part[(size_t)(b * 32 + j) * DDIM + d];
        out_exp[b * DDIM + d] = s * inv;
    }
    int l = dc * 256 + tid;
    out_p[b * LCTX + l] = e_ws[b * LCTX + l] * inv;
}

extern "C" void kernel_launch(void* const* d_in, const int* in_sizes, int n_in,
                              void* d_out, int out_size, void* d_ws, size_t ws_size,
                              hipStream_t stream) {
    const float* ctx   = (const float*)d_in[0];
    const float* query = (const float*)d_in[1];
    const int*   mask  = (const int*)d_in[2];
    const float* W1    = (const float*)d_in[3];
    const float* b1    = (const float*)d_in[4];
    const float* v     = (const float*)d_in[5];
    const float* g     = (const float*)d_in[6];
    const float* b2    = (const float*)d_in[7];
    float* out_exp = (float*)d_out;              // [16,1024]
    float* out_p   = (float*)d_out + 16384;      // [16,2048]

    char* ws = (char*)d_ws;
    unsigned short* Wc_sw = (unsigned short*)ws;          // 512 KB
    float* qproj = (float*)(ws + 524288);                 // 16 KB
    float* w2    = (float*)(ws + 540672);                 // 1 KB
    float* e_ws  = (float*)(ws + 541696);                 // 128 KB (16x2048)
    float* esum  = (float*)(ws + 672768);                 // 2 KB  (512)
    float* part  = (float*)(ws + 674816);                 // 2 MB  (512x1024)

    k_prep <<<dim3(1281),    256, 0, stream>>>(query, W1, b1, v, g, qproj, Wc_sw, w2);
    k_score<<<dim3(512),     256, 0, stream>>>(ctx, Wc_sw, qproj, w2, b2, mask, e_ws, esum);
    k_exp  <<<dim3(16, 32),  256, 0, stream>>>(ctx, e_ws, part);
    k_norm <<<dim3(16, 8),   256, 0, stream>>>(e_ws, esum, part, out_exp, out_p);
}

// Round 8
// 61.677 us; speedup vs baseline: 1.4710x; 1.1360x over previous
//
#include <hip/hip_runtime.h>
#include <hip/hip_bf16.h>

#define BB 16
#define LCTX 2048
#define DDIM 1024
#define QDIM 1024
#define HDIM 256

typedef __attribute__((ext_vector_type(8))) short short8;
typedef __attribute__((ext_vector_type(4))) float f32x4;

__device__ inline unsigned short f2bf(float x) {
    unsigned int u = __float_as_uint(x);
    unsigned int r = (u + 0x7fffu + ((u >> 16) & 1u)) >> 16;
    return (unsigned short)r;
}

// ---------------- K1: fused prep ----------------
__global__ __launch_bounds__(256) void k_prep(const float* __restrict__ query,
                                              const float* __restrict__ W1,
                                              const float* __restrict__ b1,
                                              const float* __restrict__ v,
                                              const float* __restrict__ g,
                                              float* __restrict__ qproj,
                                              unsigned short* __restrict__ Wc_sw,
                                              float* __restrict__ w2) {
    int bid = blockIdx.x;
    if (bid < 1024) {
        int b = bid >> 6;
        int hq = bid & 63;
        int wid = threadIdx.x >> 6, lane = threadIdx.x & 63;
        int h = hq * 4 + wid;
        const float* q = query + b * QDIM;
        const float* w = W1 + (size_t)h * (DDIM + QDIM) + DDIM;
        float s = 0.f;
        #pragma unroll 4
        for (int k = lane; k < QDIM; k += 64) s += q[k] * w[k];
        #pragma unroll
        for (int o = 32; o; o >>= 1) s += __shfl_down(s, o);
        if (lane == 0) qproj[b * HDIM + h] = s + b1[h];
    } else if (bid < 1280) {
        int h = bid - 1024;
        const float* src = W1 + (size_t)h * (DDIM + QDIM);
        int hx = h & 7;
        for (int d = threadIdx.x; d < DDIM; d += 256) {
            int kt = d >> 6;
            int s  = (d >> 3) & 7;
            int dl = d & 7;
            int dp = (kt << 6) + ((s ^ hx) << 3) + dl;
            Wc_sw[h * DDIM + dp] = f2bf(src[d]);
        }
    } else {
        __shared__ float red[256];
        float vv = (threadIdx.x < HDIM) ? v[threadIdx.x] : 0.f;
        red[threadIdx.x] = vv * vv;
        __syncthreads();
        for (int o = 128; o; o >>= 1) {
            if (threadIdx.x < o) red[threadIdx.x] += red[threadIdx.x + o];
            __syncthreads();
        }
        float nrm = sqrtf(red[0]);
        if (threadIdx.x < HDIM) w2[threadIdx.x] = g[0] * vv / nrm;
    }
}

// ---------------- K2: wave-autonomous ctx stream, DEPTH-2 prefetch ----------------
// Wave = 16 rows x 256 h. A: global->reg (3 rotating sets, issued 2 K-steps
// ahead => ~1300cy in flight > 900cy HBM latency). W: dbuf LDS gload_lds,
// own-wave vmcnt(4) + raw barrier, never drained to 0 until the last step.
__global__ __launch_bounds__(256, 2) void k_score(const float* __restrict__ ctx,
                                                  const unsigned short* __restrict__ Wc_sw,
                                                  const float* __restrict__ qproj,
                                                  const float* __restrict__ w2,
                                                  const float* __restrict__ b2p,
                                                  const int* __restrict__ mask,
                                                  float* __restrict__ e_ws,
                                                  float* __restrict__ esum_ws,
                                                  float* __restrict__ part) {
    __shared__ unsigned short Wt[2][256 * 64];   // 64 KB dbuf
    __shared__ float sbe[64];
    int tid = threadIdx.x;
    int wid = tid >> 6, lane = tid & 63;
    int hl = lane & 15, lhi = lane >> 4;
    int row0 = blockIdx.x * 64;
    int b = row0 >> 11;

    f32x4 acc[16];
    #pragma unroll
    for (int ht = 0; ht < 16; ht++) acc[ht] = (f32x4){0.f, 0.f, 0.f, 0.f};

    const float* abase = ctx + (size_t)(row0 + wid * 16 + hl) * DDIM + lhi * 8;

    float4 x0, x1, x2, x3;   // A set 0
    float4 y0, y1, y2, y3;   // A set 1
    float4 z0, z1, z2, z3;   // A set 2

#define STAGE_W(BUF, KT) do { \
    _Pragma("unroll") \
    for (int i_ = 0; i_ < 8; i_++) { \
        const unsigned short* gsrc_ = Wc_sw + (size_t)(wid * 64 + i_ * 8 + (lane >> 3)) * DDIM + (KT) * 64 + (lane & 7) * 8; \
        __builtin_amdgcn_global_load_lds( \
            (const __attribute__((address_space(1))) unsigned int*)gsrc_, \
            (__attribute__((address_space(3))) unsigned int*)(&Wt[BUF][(wid * 64 + i_ * 8) * 64]), \
            16, 0, 0); \
    } } while (0)

#define ISSUE_A(KT, R0, R1, R2, R3) do { \
    const float* p_ = abase + (KT) * 64; \
    R0 = *(const float4*)(p_ + 0);  R1 = *(const float4*)(p_ + 4); \
    R2 = *(const float4*)(p_ + 32); R3 = *(const float4*)(p_ + 36); } while (0)

// BODY: WAITN = manual vmcnt; DO_W/DO_A = tail gating; C* = consume set; N* = issue set
#define BODY(KT, WAITN, DO_W, DO_A, C0, C1, C2, C3, N0, N1, N2, N3) do { \
    asm volatile("s_waitcnt vmcnt(" #WAITN ")" ::: "memory"); \
    __builtin_amdgcn_sched_barrier(0); \
    __builtin_amdgcn_s_barrier(); \
    __builtin_amdgcn_sched_barrier(0); \
    if (DO_W) { STAGE_W(((KT) + 1) & 1, (KT) + 1); } \
    if (DO_A) { ISSUE_A((KT) + 2, N0, N1, N2, N3); } \
    __builtin_amdgcn_sched_barrier(0); \
    short8 af0_ = { (short)f2bf(C0.x), (short)f2bf(C0.y), (short)f2bf(C0.z), (short)f2bf(C0.w), \
                    (short)f2bf(C1.x), (short)f2bf(C1.y), (short)f2bf(C1.z), (short)f2bf(C1.w) }; \
    short8 af1_ = { (short)f2bf(C2.x), (short)f2bf(C2.y), (short)f2bf(C2.z), (short)f2bf(C2.w), \
                    (short)f2bf(C3.x), (short)f2bf(C3.y), (short)f2bf(C3.z), (short)f2bf(C3.w) }; \
    __builtin_amdgcn_s_setprio(1); \
    _Pragma("unroll") \
    for (int ht_ = 0; ht_ < 16; ht_++) { \
        short8 bf0_ = *(const short8*)(&Wt[(KT) & 1][(ht_ * 16 + hl) * 64 + ((lhi ^ (hl & 7)) << 3)]); \
        acc[ht_] = __builtin_amdgcn_mfma_f32_16x16x32_bf16(af0_, bf0_, acc[ht_], 0, 0, 0); \
    } \
    _Pragma("unroll") \
    for (int ht_ = 0; ht_ < 16; ht_++) { \
        short8 bf1_ = *(const short8*)(&Wt[(KT) & 1][(ht_ * 16 + hl) * 64 + (((4 + lhi) ^ (hl & 7)) << 3)]); \
        acc[ht_] = __builtin_amdgcn_mfma_f32_16x16x32_bf16(af1_, bf1_, acc[ht_], 0, 0, 0); \
    } \
    __builtin_amdgcn_s_setprio(0); } while (0)

    // ---- prologue: queue (oldest->newest) = [W(0).8, A(0).4, A(1).4] ----
    STAGE_W(0, 0);
    ISSUE_A(0, x0, x1, x2, x3);
    ISSUE_A(1, y0, y1, y2, y3);
    __builtin_amdgcn_sched_barrier(0);

    //        KT  wait W A   consume        issue(KT+2)
    BODY( 0,  8, 1, 1,  x0, x1, x2, x3,  z0, z1, z2, z3);
    BODY( 1,  4, 1, 1,  y0, y1, y2, y3,  x0, x1, x2, x3);
    BODY( 2,  4, 1, 1,  z0, z1, z2, z3,  y0, y1, y2, y3);
    BODY( 3,  4, 1, 1,  x0, x1, x2, x3,  z0, z1, z2, z3);
    BODY( 4,  4, 1, 1,  y0, y1, y2, y3,  x0, x1, x2, x3);
    BODY( 5,  4, 1, 1,  z0, z1, z2, z3,  y0, y1, y2, y3);
    BODY( 6,  4, 1, 1,  x0, x1, x2, x3,  z0, z1, z2, z3);
    BODY( 7,  4, 1, 1,  y0, y1, y2, y3,  x0, x1, x2, x3);
    BODY( 8,  4, 1, 1,  z0, z1, z2, z3,  y0, y1, y2, y3);
    BODY( 9,  4, 1, 1,  x0, x1, x2, x3,  z0, z1, z2, z3);
    BODY(10,  4, 1, 1,  y0, y1, y2, y3,  x0, x1, x2, x3);
    BODY(11,  4, 1, 1,  z0, z1, z2, z3,  y0, y1, y2, y3);
    BODY(12,  4, 1, 1,  x0, x1, x2, x3,  z0, z1, z2, z3);
    BODY(13,  4, 1, 1,  y0, y1, y2, y3,  x0, x1, x2, x3);
    BODY(14,  4, 1, 0,  z0, z1, z2, z3,  y0, y1, y2, y3);
    BODY(15,  0, 0, 0,  x0, x1, x2, x3,  y0, y1, y2, y3);

    // ---- epilogue: tanh + w2 dot; wave owns whole rows -> 16-lane reduce ----
    float qp[16], wv[16];
    #pragma unroll
    for (int ht = 0; ht < 16; ht++) {
        qp[ht] = qproj[b * HDIM + ht * 16 + hl];
        wv[ht] = w2[ht * 16 + hl];
    }
    float bias2 = b2p[0];
    #pragma unroll
    for (int r = 0; r < 4; r++) {
        float partial = 0.f;
        #pragma unroll
        for (int ht = 0; ht < 16; ht++) {
            float x = acc[ht][r] + qp[ht];
            x = fminf(fmaxf(x, -15.f), 15.f);
            float e2 = __expf(2.f * x);
            partial += (e2 - 1.f) / (e2 + 1.f) * wv[ht];
        }
        #pragma unroll
        for (int o = 1; o < 16; o <<= 1) partial += __shfl_xor(partial, o);
        if (hl == 0) {
            int lrow = wid * 16 + lhi * 4 + r;
            int grow = row0 + lrow;
            float s = partial + bias2;
            float e = (mask[b * 2048 + (grow & 2047)] == 1) ? 0.f : __expf(s);
            e_ws[grow] = e;
            sbe[lrow] = e;
        }
    }
    __syncthreads();

    if (tid < 64) {
        float tot = sbe[tid];
        #pragma unroll
        for (int o = 32; o; o >>= 1) tot += __shfl_down(tot, o);
        if (tid == 0) esum_ws[blockIdx.x] = tot;
    }

    // ---- fused partial GEMV (tile is L2/L3-hot; R7 proved fusing saves ~11us) ----
    {
        int d0 = tid * 4;
        const float* cb = ctx + (size_t)row0 * DDIM + d0;
        float4 a = {0.f, 0.f, 0.f, 0.f};
        #pragma unroll 8
        for (int l = 0; l < 64; l++) {
            float el = sbe[l];
            float4 cc = *(const float4*)(cb + (size_t)l * DDIM);
            a.x += el * cc.x; a.y += el * cc.y; a.z += el * cc.z; a.w += el * cc.w;
        }
        *(float4*)(part + (size_t)blockIdx.x * DDIM + d0) = a;
    }
}

// ---------------- K3: normalize -> out_exp, out_p ----------------
__global__ __launch_bounds__(256) void k_norm(const float* __restrict__ e_ws,
                                              const float* __restrict__ esum_ws,
                                              const float* __restrict__ part,
                                              float* __restrict__ out_exp,
                                              float* __restrict__ out_p) {
    int b = blockIdx.x, dc = blockIdx.y;
    int tid = threadIdx.x;
    float se = 0.f;
    #pragma unroll
    for (int j = 0; j < 32; j++) se += esum_ws[b * 32 + j];
    float inv = 1.f / se;
    if (tid < 128) {
        int d = dc * 128 + tid;
        float s = 0.f;
        #pragma unroll
        for (int j = 0; j < 32; j++) s += part[(size_t)(b * 32 + j) * DDIM + d];
        out_exp[b * DDIM + d] = s * inv;
    }
    int l = dc * 256 + tid;
    out_p[b * LCTX + l] = e_ws[b * LCTX + l] * inv;
}

extern "C" void kernel_launch(void* const* d_in, const int* in_sizes, int n_in,
                              void* d_out, int out_size, void* d_ws, size_t ws_size,
                              hipStream_t stream) {
    const float* ctx   = (const float*)d_in[0];
    const float* query = (const float*)d_in[1];
    const int*   mask  = (const int*)d_in[2];
    const float* W1    = (const float*)d_in[3];
    const float* b1    = (const float*)d_in[4];
    const float* v     = (const float*)d_in[5];
    const float* g     = (const float*)d_in[6];
    const float* b2    = (const float*)d_in[7];
    float* out_exp = (float*)d_out;              // [16,1024]
    float* out_p   = (float*)d_out + 16384;      // [16,2048]

    char* ws = (char*)d_ws;
    unsigned short* Wc_sw = (unsigned short*)ws;          // 512 KB
    float* qproj = (float*)(ws + 524288);                 // 16 KB
    float* w2    = (float*)(ws + 540672);                 // 1 KB
    float* e_ws  = (float*)(ws + 541696);                 // 128 KB (16x2048)
    float* esum  = (float*)(ws + 672768);                 // 2 KB  (512)
    float* part  = (float*)(ws + 674816);                 // 2 MB  (512x1024)

    k_prep <<<dim3(1281),   256, 0, stream>>>(query, W1, b1, v, g, qproj, Wc_sw, w2);
    k_score<<<dim3(512),    256, 0, stream>>>(ctx, Wc_sw, qproj, w2, b2, mask, e_ws, esum, part);
    k_norm <<<dim3(16, 8),  256, 0, stream>>>(e_ws, esum, part, out_exp, out_p);
}

// Round 9
// 59.588 us; speedup vs baseline: 1.5225x; 1.0351x over previous
//
#include <hip/hip_runtime.h>
#include <hip/hip_bf16.h>

#define BB 16
#define LCTX 2048
#define DDIM 1024
#define QDIM 1024
#define HDIM 256

typedef __attribute__((ext_vector_type(8))) short short8;
typedef __attribute__((ext_vector_type(4))) short short4v;
typedef __attribute__((ext_vector_type(4))) float f32x4;

__device__ inline unsigned short f2bf(float x) {
    unsigned int u = __float_as_uint(x);
    unsigned int r = (u + 0x7fffu + ((u >> 16) & 1u)) >> 16;
    return (unsigned short)r;
}

// ---------------- K1: fused prep ----------------
// bid <  1024 : qproj[b][h] = query[b] . Wq[h] + b1[h]
// 1024..1279  : Wc row (h) -> bf16, chunks pre-swizzled for LDS
// bid == 1280 : w2 = g * v / ||v||
__global__ __launch_bounds__(256) void k_prep(const float* __restrict__ query,
                                              const float* __restrict__ W1,
                                              const float* __restrict__ b1,
                                              const float* __restrict__ v,
                                              const float* __restrict__ g,
                                              float* __restrict__ qproj,
                                              unsigned short* __restrict__ Wc_sw,
                                              float* __restrict__ w2) {
    int bid = blockIdx.x;
    if (bid < 1024) {
        int b = bid >> 6;
        int hq = bid & 63;
        int wid = threadIdx.x >> 6, lane = threadIdx.x & 63;
        int h = hq * 4 + wid;
        const float* q = query + b * QDIM;
        const float* w = W1 + (size_t)h * (DDIM + QDIM) + DDIM;
        float s = 0.f;
        #pragma unroll 4
        for (int k = lane; k < QDIM; k += 64) s += q[k] * w[k];
        #pragma unroll
        for (int o = 32; o; o >>= 1) s += __shfl_down(s, o);
        if (lane == 0) qproj[b * HDIM + h] = s + b1[h];
    } else if (bid < 1280) {
        int h = bid - 1024;
        const float* src = W1 + (size_t)h * (DDIM + QDIM);
        int hx = h & 7;
        for (int d = threadIdx.x; d < DDIM; d += 256) {
            int kt = d >> 6;
            int s  = (d >> 3) & 7;      // 16B chunk within 64-col k-tile
            int dl = d & 7;
            int dp = (kt << 6) + ((s ^ hx) << 3) + dl;
            Wc_sw[h * DDIM + dp] = f2bf(src[d]);
        }
    } else {
        __shared__ float red[256];
        float vv = (threadIdx.x < HDIM) ? v[threadIdx.x] : 0.f;
        red[threadIdx.x] = vv * vv;
        __syncthreads();
        for (int o = 128; o; o >>= 1) {
            if (threadIdx.x < o) red[threadIdx.x] += red[threadIdx.x + o];
            __syncthreads();
        }
        float nrm = sqrtf(red[0]);
        if (threadIdx.x < HDIM) w2[threadIdx.x] = g[0] * vv / nrm;
    }
}

// ---------------- K2: R2-fused structure, TRANSACTION-MINIMAL ctx staging ----------------
// Only change vs the 59.1us R2-fused kernel: ctx staging lane map is now
// full-row-contiguous (instr i covers 4 whole rows; lane l reads 16 B at
// (l&15)*16 within its row) -> 16 cache lines/instr instead of 64.
__global__ __launch_bounds__(256, 3) void k_score(const float* __restrict__ ctx,
                                                  const unsigned short* __restrict__ Wc_sw,
                                                  const float* __restrict__ qproj,
                                                  const float* __restrict__ w2,
                                                  const float* __restrict__ b2p,
                                                  const int* __restrict__ mask,
                                                  float* __restrict__ e_ws,
                                                  float* __restrict__ esum_ws,
                                                  float* __restrict__ part) {
    __shared__ unsigned short At[64 * 64];    // 8 KB, XOR-swizzled
    __shared__ unsigned short Wt[256 * 64];   // 32 KB, pre-swizzled in global
    int tid = threadIdx.x;
    int wid = tid >> 6, lane = tid & 63;
    int hl = lane & 15, lhi = lane >> 4;
    int bid = blockIdx.x;
    int row0 = bid * 64;
    int b = row0 >> 11;

    float qp[4], wv[4];
    #pragma unroll
    for (int ht = 0; ht < 4; ht++) {
        int h = wid * 64 + ht * 16 + hl;
        qp[ht] = qproj[b * HDIM + h];
        wv[ht] = w2[h];
    }

    f32x4 acc[4][4];
    #pragma unroll
    for (int mt = 0; mt < 4; mt++)
        #pragma unroll
        for (int ht = 0; ht < 4; ht++)
            acc[mt][ht] = (f32x4){0.f, 0.f, 0.f, 0.f};

    // ctx staging: lane l serves rows wid*16 + i*4 + (l>>4), floats (l&15)*4..+4
    int srow_base = wid * 16 + (lane >> 4);     // + i*4
    int scol = (lane & 15) * 4;                 // float col within 64-col k-tile
    int chunk = (lane & 15) >> 1;               // 16B chunk index 0..7
    int half8 = (lane & 1) * 4;                 // 8B half within chunk (elements)

    for (int kt = 0; kt < 16; kt++) {
        // stage W tile: 32 KB via global_load_lds (linear dest; src pre-swizzled)
        #pragma unroll
        for (int i = 0; i < 8; i++) {
            int n = i * 256 + tid;
            const unsigned short* gsrc = Wc_sw + (size_t)(n >> 3) * DDIM + kt * 64 + (n & 7) * 8;
            __builtin_amdgcn_global_load_lds(
                (const __attribute__((address_space(1))) unsigned int*)gsrc,
                (__attribute__((address_space(3))) unsigned int*)(Wt + (i * 256 + (tid & ~63)) * 8),
                16, 0, 0);
        }
        // stage ctx tile: full-row-contiguous (16 lines/instr), f2bf, ds_write_b64
        #pragma unroll
        for (int i = 0; i < 4; i++) {
            int lrow = srow_base + i * 4;
            const float* cp = ctx + (size_t)(row0 + lrow) * DDIM + kt * 64 + scol;
            float4 cv = *(const float4*)cp;
            short4v hv = { (short)f2bf(cv.x), (short)f2bf(cv.y),
                           (short)f2bf(cv.z), (short)f2bf(cv.w) };
            *(short4v*)(At + lrow * 64 + ((chunk ^ (lrow & 7)) << 3) + half8) = hv;
        }
        __syncthreads();

        #pragma unroll
        for (int ks = 0; ks < 2; ks++) {
            int s = ks * 4 + lhi;
            short8 af[4], bfr[4];
            #pragma unroll
            for (int mt = 0; mt < 4; mt++) {
                int m = mt * 16 + hl;
                af[mt] = *(const short8*)(At + m * 64 + ((s ^ (m & 7)) << 3));
            }
            #pragma unroll
            for (int ht = 0; ht < 4; ht++) {
                int h = wid * 64 + ht * 16 + hl;
                bfr[ht] = *(const short8*)(Wt + h * 64 + ((s ^ (h & 7)) << 3));
            }
            #pragma unroll
            for (int mt = 0; mt < 4; mt++)
                #pragma unroll
                for (int ht = 0; ht < 4; ht++)
                    acc[mt][ht] = __builtin_amdgcn_mfma_f32_16x16x32_bf16(af[mt], bfr[ht], acc[mt][ht], 0, 0, 0);
        }
        __syncthreads();
    }

    // ---- epilogue 1: tanh + w2 dot, reduce 16 lanes, cross-wave via LDS ----
    float* sb  = (float*)At;        // 256 floats (cross-wave partials)
    float* sbe = sb + 256;          // 64 floats (e per row)
    #pragma unroll
    for (int mt = 0; mt < 4; mt++) {
        #pragma unroll
        for (int r = 0; r < 4; r++) {
            float partial = 0.f;
            #pragma unroll
            for (int ht = 0; ht < 4; ht++) {
                float x = acc[mt][ht][r] + qp[ht];
                x = fminf(fmaxf(x, -15.f), 15.f);
                float e2 = __expf(2.f * x);
                partial += (e2 - 1.f) / (e2 + 1.f) * wv[ht];
            }
            #pragma unroll
            for (int o = 1; o < 16; o <<= 1) partial += __shfl_xor(partial, o);
            if (hl == 0) sb[wid * 64 + mt * 16 + lhi * 4 + r] = partial;
        }
    }
    __syncthreads();

    // ---- epilogue 2: score -> e = exp(score) (masked -> 0) ----
    if (tid < 64) {
        float s = sb[tid] + sb[64 + tid] + sb[128 + tid] + sb[192 + tid] + b2p[0];
        int grow = row0 + tid;
        float e = (mask[b * 2048 + (grow & 2047)] == 1) ? 0.f : __expf(s);
        e_ws[grow] = e;
        sbe[tid] = e;
        float tot = e;
        #pragma unroll
        for (int o = 32; o; o >>= 1) tot += __shfl_down(tot, o);
        if (tid == 0) esum_ws[bid] = tot;
    }
    __syncthreads();

    // ---- epilogue 3: fused partial GEMV (tile L2/L3-hot; lanes contiguous) ----
    {
        int d0 = tid * 4;
        const float* cb = ctx + (size_t)row0 * DDIM + d0;
        float4 a = {0.f, 0.f, 0.f, 0.f};
        #pragma unroll 8
        for (int l = 0; l < 64; l++) {
            float el = sbe[l];
            float4 cc = *(const float4*)(cb + (size_t)l * DDIM);
            a.x += el * cc.x; a.y += el * cc.y; a.z += el * cc.z; a.w += el * cc.w;
        }
        *(float4*)(part + (size_t)bid * DDIM + d0) = a;
    }
}

// ---------------- K3: normalize -> out_exp, out_p ----------------
__global__ __launch_bounds__(256) void k_norm(const float* __restrict__ e_ws,
                                              const float* __restrict__ esum_ws,
                                              const float* __restrict__ part,
                                              float* __restrict__ out_exp,
                                              float* __restrict__ out_p) {
    int b = blockIdx.x, dc = blockIdx.y;
    int tid = threadIdx.x;
    float se = 0.f;
    #pragma unroll
    for (int j = 0; j < 32; j++) se += esum_ws[b * 32 + j];
    float inv = 1.f / se;
    if (tid < 128) {
        int d = dc * 128 + tid;
        float s = 0.f;
        #pragma unroll
        for (int j = 0; j < 32; j++) s += part[(size_t)(b * 32 + j) * DDIM + d];
        out_exp[b * DDIM + d] = s * inv;
    }
    int l = dc * 256 + tid;
    out_p[b * LCTX + l] = e_ws[b * LCTX + l] * inv;
}

extern "C" void kernel_launch(void* const* d_in, const int* in_sizes, int n_in,
                              void* d_out, int out_size, void* d_ws, size_t ws_size,
                              hipStream_t stream) {
    const float* ctx   = (const float*)d_in[0];
    const float* query = (const float*)d_in[1];
    const int*   mask  = (const int*)d_in[2];
    const float* W1    = (const float*)d_in[3];
    const float* b1    = (const float*)d_in[4];
    const float* v     = (const float*)d_in[5];
    const float* g     = (const float*)d_in[6];
    const float* b2    = (const float*)d_in[7];
    float* out_exp = (float*)d_out;              // [16,1024]
    float* out_p   = (float*)d_out + 16384;      // [16,2048]

    char* ws = (char*)d_ws;
    unsigned short* Wc_sw = (unsigned short*)ws;          // 512 KB
    float* qproj = (float*)(ws + 524288);                 // 16 KB
    float* w2    = (float*)(ws + 540672);                 // 1 KB
    float* e_ws  = (float*)(ws + 541696);                 // 128 KB (16x2048)
    float* esum  = (float*)(ws + 672768);                 // 2 KB  (512)
    float* part  = (float*)(ws + 674816);                 // 2 MB  (512x1024)

    k_prep <<<dim3(1281),   256, 0, stream>>>(query, W1, b1, v, g, qproj, Wc_sw, w2);
    k_score<<<dim3(512),    256, 0, stream>>>(ctx, Wc_sw, qproj, w2, b2, mask, e_ws, esum, part);
    k_norm <<<dim3(16, 8),  256, 0, stream>>>(e_ws, esum, part, out_exp, out_p);
}